// Round 16
// baseline (845.838 us; speedup 1.0000x reference)
//
#include <hip/hip_runtime.h>
#include <math.h>

#define BB 4
#define SS 2048
#define INDIM 4
#define DD 128
#define HH 8
#define DH 16
#define DEPTH 6
#define BUCKET 64
#define NHASH 8
#define NBK 32                 // buckets per hash round
#define DFF 512
#define LL (NHASH*SS)          // 16384 per (b,h)
#define NCHUNK (NHASH*NBK)     // 256 chunks per (b,h)
#define NBH (BB*HH)            // 32

typedef short bf16x8 __attribute__((ext_vector_type(8)));
typedef _Float16 f16x8 __attribute__((ext_vector_type(8)));
typedef _Float16 f16x2 __attribute__((ext_vector_type(2)));
typedef float f32x4 __attribute__((ext_vector_type(4)));

__device__ __forceinline__ unsigned short f2bf(float f) {
    unsigned u = __builtin_bit_cast(unsigned, f);
    unsigned r = u + 0x7FFFu + ((u >> 16) & 1u);   // RTNE
    return (unsigned short)(r >> 16);
}

// ---------------- embedding: h = x @ embW + embb ----------------
__global__ void k_embed(const float* __restrict__ x, const float* __restrict__ W,
                        const float* __restrict__ b, float* __restrict__ h) {
    int idx = blockIdx.x * blockDim.x + threadIdx.x;   // B*S*D
    if (idx >= BB*SS*DD) return;
    int d = idx % DD, bs = idx / DD;
    const float* xr = x + bs*INDIM;
    float acc = b[d];
    #pragma unroll
    for (int k = 0; k < INDIM; k++) acc += xr[k] * W[k*DD + d];
    h[idx] = acc;
}

// ---------------- weight transpose + bf16 cast: dst[c][r] = bf16(src[r][c]) ----------------
__global__ void k_wcast(const float* __restrict__ src, unsigned short* __restrict__ dst,
                        int R, int C) {
    __shared__ float tile[32][33];
    int l = blockIdx.z;
    const float* s = src + (size_t)l*R*C;
    unsigned short* d = dst + (size_t)l*R*C;
    int c0 = blockIdx.x*32, r0 = blockIdx.y*32;
    int tx = threadIdx.x, ty = threadIdx.y;   // 32 x 8
    #pragma unroll
    for (int i = 0; i < 4; i++)
        tile[ty + i*8][tx] = s[(size_t)(r0 + ty + i*8)*C + c0 + tx];
    __syncthreads();
    #pragma unroll
    for (int i = 0; i < 4; i++)
        d[(size_t)(c0 + ty + i*8)*R + r0 + tx] = f2bf(tile[tx][ty + i*8]);
}

// ---------------- weight transpose + fp16 cast ----------------
__global__ void k_wcast16(const float* __restrict__ src, _Float16* __restrict__ dst,
                          int R, int C) {
    __shared__ float tile[32][33];
    int l = blockIdx.z;
    const float* s = src + (size_t)l*R*C;
    _Float16* d = dst + (size_t)l*R*C;
    int c0 = blockIdx.x*32, r0 = blockIdx.y*32;
    int tx = threadIdx.x, ty = threadIdx.y;   // 32 x 8
    #pragma unroll
    for (int i = 0; i < 4; i++)
        tile[ty + i*8][tx] = s[(size_t)(r0 + ty + i*8)*C + c0 + tx];
    __syncthreads();
    #pragma unroll
    for (int i = 0; i < 4; i++)
        d[(size_t)(c0 + ty + i*8)*R + r0 + tx] = (_Float16)tile[tx][ty + i*8];
}

// ---------------- fused LN1 + qk/v projections: fp16 MFMA, 16 rows/block ----------------
// Outputs only attention-ready operands: kn16 = normalized K (fp16), v16 (fp16),
// nrm = |q|*0.25*log2e (fp32). The hash uses kn16 (argmax is scale-invariant).
__global__ __launch_bounds__(256, 4)
void k_proj_qkv(const float* __restrict__ hin, const float* __restrict__ lng,
                const float* __restrict__ lnb, const _Float16* __restrict__ WqkT,
                const _Float16* __restrict__ WvT,
                _Float16* __restrict__ kn16, _Float16* __restrict__ v16,
                float* __restrict__ nrmg) {
    __shared__ float A[16][128];
    __shared__ __align__(16) _Float16 Lf[16][136];
    int row0 = blockIdx.x * 16;
    int t = threadIdx.x;                  // 256
    {
        const float4* src = (const float4*)(hin + (size_t)row0*DD);
        float4* dst = (float4*)&A[0][0];
        dst[t]       = src[t];
        dst[t + 256] = src[t + 256];
    }
    __syncthreads();
    // layernorm: 16 threads per row, 8 elems each -> fp16 tile
    {
        int r = t >> 4, sub = t & 15;
        float4 xa = *(const float4*)&A[r][sub*8];
        float4 xb = *(const float4*)&A[r][sub*8 + 4];
        float s = xa.x+xa.y+xa.z+xa.w + xb.x+xb.y+xb.z+xb.w;
        s += __shfl_xor(s,1); s += __shfl_xor(s,2);
        s += __shfl_xor(s,4); s += __shfl_xor(s,8);
        float m = s * (1.0f/128.0f);
        float d0=xa.x-m, d1=xa.y-m, d2=xa.z-m, d3=xa.w-m;
        float d4=xb.x-m, d5=xb.y-m, d6=xb.z-m, d7=xb.w-m;
        float vs = d0*d0+d1*d1+d2*d2+d3*d3+d4*d4+d5*d5+d6*d6+d7*d7;
        vs += __shfl_xor(vs,1); vs += __shfl_xor(vs,2);
        vs += __shfl_xor(vs,4); vs += __shfl_xor(vs,8);
        float inv = 1.0f / sqrtf(vs * (1.0f/128.0f) + 1e-5f);
        float4 ga = *(const float4*)&lng[sub*8], gb = *(const float4*)&lng[sub*8+4];
        float4 ba = *(const float4*)&lnb[sub*8], bb = *(const float4*)&lnb[sub*8+4];
        f16x8 vv;
        vv[0] = (_Float16)(d0*inv*ga.x + ba.x);
        vv[1] = (_Float16)(d1*inv*ga.y + ba.y);
        vv[2] = (_Float16)(d2*inv*ga.z + ba.z);
        vv[3] = (_Float16)(d3*inv*ga.w + ba.w);
        vv[4] = (_Float16)(d4*inv*gb.x + bb.x);
        vv[5] = (_Float16)(d5*inv*gb.y + bb.y);
        vv[6] = (_Float16)(d6*inv*gb.z + bb.z);
        vv[7] = (_Float16)(d7*inv*gb.w + bb.w);
        *(f16x8*)&Lf[r][sub*8] = vv;
    }
    __syncthreads();
    int w = t >> 6, lane = t & 63;
    int fr = lane & 15, kg = lane >> 4;
    f32x4 aq[2], av[2];
    aq[0] = (f32x4){0.f,0.f,0.f,0.f}; aq[1] = (f32x4){0.f,0.f,0.f,0.f};
    av[0] = (f32x4){0.f,0.f,0.f,0.f}; av[1] = (f32x4){0.f,0.f,0.f,0.f};
    #pragma unroll
    for (int ks = 0; ks < 4; ks++) {
        f16x8 af = *(const f16x8*)&Lf[fr][ks*32 + kg*8];
        #pragma unroll
        for (int nt = 0; nt < 2; nt++) {
            const _Float16* bp = WqkT + (size_t)(w*32 + nt*16 + fr)*128 + ks*32 + kg*8;
            f16x8 bq = *(const f16x8*)bp;
            aq[nt] = __builtin_amdgcn_mfma_f32_16x16x32_f16(af, bq, aq[nt], 0, 0, 0);
            const _Float16* vp = WvT + (size_t)(w*32 + nt*16 + fr)*128 + ks*32 + kg*8;
            f16x8 bv = *(const f16x8*)vp;
            av[nt] = __builtin_amdgcn_mfma_f32_16x16x32_f16(af, bv, av[nt], 0, 0, 0);
        }
    }
    int b = row0 / SS;
    int sb = row0 & (SS-1);
    #pragma unroll
    for (int nt = 0; nt < 2; nt++) {
        int n = w*32 + nt*16 + fr;
        int h_ = n >> 4, d_ = n & 15;   // d_ == fr
        // per-row |q|^2 over the head's 16 dims (lanes fr=0..15 of this group)
        float ssq[4];
        #pragma unroll
        for (int i = 0; i < 4; i++) { float xx = aq[nt][i]; ssq[i] = xx*xx; }
        #pragma unroll
        for (int o = 1; o <= 8; o <<= 1) {
            #pragma unroll
            for (int i = 0; i < 4; i++) ssq[i] += __shfl_xor(ssq[i], o);
        }
        #pragma unroll
        for (int i = 0; i < 4; i++) {
            int s = sb + kg*4 + i;
            size_t rowi = ((size_t)(b*HH + h_))*SS + s;
            float nn = sqrtf(ssq[i]);
            float inv = 1.0f / nn;
            kn16[rowi*DH + d_] = (_Float16)(aq[nt][i] * inv);
            v16[rowi*DH + d_]  = (_Float16)(av[nt][i]);
            if (d_ == 0) nrmg[rowi] = nn * 0.25f * 1.4426950408889634f;
        }
    }
}

// ---------------- LSH hashing from normalized fp16 K (scale-invariant argmax) ----------------
__global__ void k_hash(const _Float16* __restrict__ kn16, const float* __restrict__ R,
                       int* __restrict__ bkt) {
    __shared__ float Rs[256];             // R[h_][d][n][r] for block-uniform (h_,n)
    int idx = blockIdx.x*256 + threadIdx.x;   // [bh][n][s]
    int s = idx & (SS-1); int t2 = idx >> 11;
    int n = t2 & 7; int bh = t2 >> 3; int h_ = bh & 7;
    {
        int tt = threadIdx.x;
        int d = tt >> 4, r = tt & 15;
        Rs[tt] = R[(((h_*DH + d)*NHASH + n)*16) + r];
    }
    __syncthreads();
    const f16x8* q8 = (const f16x8*)(kn16 + ((size_t)bh*SS + s)*DH);
    f16x8 qa = q8[0], qb = q8[1];
    float q[16];
    #pragma unroll
    for (int j = 0; j < 8; j++) { q[j] = (float)qa[j]; q[8+j] = (float)qb[j]; }
    float rxv[16];
    #pragma unroll
    for (int r = 0; r < 16; r++) {
        float acc = 0.f;
        #pragma unroll
        for (int d = 0; d < 16; d++) acc += q[d] * Rs[d*16 + r];
        rxv[r] = acc;
    }
    float best = rxv[0]; int bi = 0;
    #pragma unroll
    for (int jx = 1; jx < 16; jx++) if (rxv[jx]  > best) { best = rxv[jx];  bi = jx; }
    #pragma unroll
    for (int jx = 0; jx < 16; jx++) if (-rxv[jx] > best) { best = -rxv[jx]; bi = 16 + jx; }
    bkt[idx] = n*NBK + bi;
}

// ---------------- counting sort per (b,h,round) ----------------
__global__ void k_scatter(const int* __restrict__ bkt, int* __restrict__ sticker) {
    __shared__ int hist[256*33];       // padded stride 33: conflict-free columns
    __shared__ int cs[8*33];
    __shared__ int bbk[NBK];
    int blk = blockIdx.x;              // B*H*NHASH
    int n = blk & 7, bh = blk >> 3;
    int t = threadIdx.x;               // 256 threads, 8 consecutive elems each
    #pragma unroll
    for (int k = 0; k < NBK; k++) hist[t*33 + k] = 0;
    const int* bp = bkt + (size_t)bh*LL + n*SS;
    int local[8];
    #pragma unroll
    for (int e = 0; e < 8; e++) {
        int k = bp[t*8 + e] - n*NBK;
        local[e] = k;
        hist[t*33 + k]++;
    }
    __syncthreads();
    {
        int i = t >> 5, k = t & 31;
        int ssum = 0;
        #pragma unroll
        for (int rr = 0; rr < 32; rr++) ssum += hist[(i*32+rr)*33 + k];
        cs[i*33 + k] = ssum;
    }
    __syncthreads();
    if (t < 32) {
        int tot = 0;
        #pragma unroll
        for (int i = 0; i < 8; i++) tot += cs[i*33 + t];
        int x = tot;
        #pragma unroll
        for (int o = 1; o < 32; o <<= 1) {
            int y = __shfl(x, (t >= o) ? (t - o) : 0, 64);
            if (t >= o) x += y;
        }
        bbk[t] = n*SS + x - tot;        // exclusive prefix + round base
    }
    __syncthreads();
    {
        int i = t >> 5, k = t & 31;
        int run = bbk[k];
        for (int ii = 0; ii < i; ii++) run += cs[ii*33 + k];
        for (int rr = 0; rr < 32; rr++) {
            int idx = (i*32+rr)*33 + k;
            int c0 = hist[idx];
            hist[idx] = run;
            run += c0;
        }
    }
    __syncthreads();
    #pragma unroll
    for (int e = 0; e < 8; e++) {
        int k = local[e];
        int pos = hist[t*33 + k]++;
        sticker[(size_t)bh*LL + pos] = n*SS + t*8 + e;
    }
}

// ---------------- chunked look-back attention, fp16 MFMA (transposed QK) ----------------
// Kf stores only the 16 real dims ([128][24], 6KB); the K=32 MFMA's upper-half
// fragments are zero REGISTERS (kg>=2 lanes), not LDS. 28.25KB LDS -> 5 blocks/CU.
__global__ __launch_bounds__(256, 5)
void k_attn(const _Float16* __restrict__ kn16, const _Float16* __restrict__ v16,
            const float* __restrict__ nrmg, const int* __restrict__ sticker,
            _Float16* __restrict__ so, float* __restrict__ slog) {
    __shared__ __align__(16) char smem[28928];
    _Float16 (*Kf)[24]  = (_Float16(*)[24])smem;              // 128x24  = 6144
    _Float16 (*P)[136]  = (_Float16(*)[136])(smem + 6144);    // 64x136  = 17408 [q][j]
    _Float16 (*VT)[136] = (_Float16(*)[136])(smem + 23552);   // 16x136  = 4352
    int*   pk   = (int*)(smem + 27904);                       // 128 ints
    float* nrm  = (float*)(smem + 28416);                     // 64 floats (|k|*0.25*log2e)
    int*   lraw = (int*)(smem + 28672);                       // 64 ints

    int blk = blockIdx.x;              // B*H*NCHUNK
    int c = blk & (NCHUNK-1), bh = blk >> 8;
    int t = threadIdx.x;
    const int* stk = sticker + (size_t)bh*LL;

    // ---- stage: 32B fp16 loads, zero arithmetic ----
    if (t < 128) {
        int j = t;
        int cc = (j < 64) ? c : ((c + NCHUNK - 1) & (NCHUNK-1));
        int raw = stk[cc*BUCKET + (j & 63)];
        int sk = raw & (SS-1);
        const f16x8* kp = (const f16x8*)(kn16 + ((size_t)bh*SS + sk)*DH);
        *(f16x8*)&Kf[j][0] = kp[0];
        *(f16x8*)&Kf[j][8] = kp[1];
        pk[j] = sk;
        if (j < 64) { nrm[j] = nrmg[(size_t)bh*SS + sk]; lraw[j] = raw; }
    } else {
        int j = t - 128;
        int cc = (j < 64) ? c : ((c + NCHUNK - 1) & (NCHUNK-1));
        int sk = stk[cc*BUCKET + (j & 63)] & (SS-1);
        const f16x8* vp = (const f16x8*)(v16 + ((size_t)bh*SS + sk)*DH);
        f16x8 v0 = vp[0], v1 = vp[1];
        VT[ 0][j]=v0[0]; VT[ 1][j]=v0[1]; VT[ 2][j]=v0[2]; VT[ 3][j]=v0[3];
        VT[ 4][j]=v0[4]; VT[ 5][j]=v0[5]; VT[ 6][j]=v0[6]; VT[ 7][j]=v0[7];
        VT[ 8][j]=v1[0]; VT[ 9][j]=v1[1]; VT[10][j]=v1[2]; VT[11][j]=v1[3];
        VT[12][j]=v1[4]; VT[13][j]=v1[5]; VT[14][j]=v1[6]; VT[15][j]=v1[7];
    }
    __syncthreads();

    int w = t >> 6, lane = t & 63;
    int fr = lane & 15, kg = lane >> 4;
    int qrow = w*16 + fr;

    // ---- QK^T transposed: acc[nt] holds S^T[j=nt*16+kg*4+i][q=w*16+fr] ----
    f32x4 acc[8];
    #pragma unroll
    for (int nt = 0; nt < 8; nt++) acc[nt] = (f32x4){0.f,0.f,0.f,0.f};
    {
        f16x8 z = {0,0,0,0,0,0,0,0};
        f16x8 bq = z;
        if (kg < 2) {
            f16x8 kfq = *(const f16x8*)&Kf[qrow][kg*8];
            _Float16 qs = (_Float16)nrm[qrow];
            bq = kfq * qs;                       // B operand: Q (log2-scaled)
        }
        #pragma unroll
        for (int nt = 0; nt < 8; nt++) {
            f16x8 afk = z;
            if (kg < 2) afk = *(const f16x8*)&Kf[nt*16 + fr][kg*8];  // A: K rows
            acc[nt] = __builtin_amdgcn_mfma_f32_16x16x32_f16(afk, bq, acc[nt], 0, 0, 0);
        }
    }
    // ---- mask + exp2 -> packed P[q][j] (same-wave rows), sum over j local ----
    int pq_self = pk[qrow];
    float s = 0.f;
    #pragma unroll
    for (int nt = 0; nt < 8; nt++) {
        int4 pk4 = *(const int4*)&pk[nt*16 + kg*4];
        float d0 = (pk4.x == pq_self) ? -5e4f : acc[nt][0];
        float d1 = (pk4.y == pq_self) ? -5e4f : acc[nt][1];
        float d2 = (pk4.z == pq_self) ? -5e4f : acc[nt][2];
        float d3 = (pk4.w == pq_self) ? -5e4f : acc[nt][3];
        float p0 = exp2f(d0), p1 = exp2f(d1), p2 = exp2f(d2), p3 = exp2f(d3);
        s += (p0 + p1) + (p2 + p3);
        f16x2 w0 = {(_Float16)p0, (_Float16)p1};
        f16x2 w1 = {(_Float16)p2, (_Float16)p3};
        *(f16x2*)&P[qrow][nt*16 + kg*4]     = w0;
        *(f16x2*)&P[qrow][nt*16 + kg*4 + 2] = w1;
    }
    s += __shfl_xor(s, 16);
    s += __shfl_xor(s, 32);
    if (kg == 0) slog[(size_t)bh*LL + lraw[qrow]] = __logf(s);
    // no barrier: P rows for wave w written and read by wave w only

    // ---- PV: wave w computes rows w*16..+15 x 16 dims (unnormalized) ----
    f32x4 oacc = (f32x4){0.f,0.f,0.f,0.f};
    #pragma unroll
    for (int ks = 0; ks < 4; ks++) {
        f16x8 af = *(const f16x8*)&P[w*16 + fr][ks*32 + kg*8];
        f16x8 bf = *(const f16x8*)&VT[fr][ks*32 + kg*8];
        oacc = __builtin_amdgcn_mfma_f32_16x16x32_f16(af, bf, oacc, 0, 0, 0);
    }
    // ---- scatter-write unnormalized o (unsorted order, fp16) ----
    {
        int4 lr4 = *(const int4*)&lraw[w*16 + kg*4];
        so[((size_t)bh*LL + lr4.x)*DH + fr] = (_Float16)oacc[0];
        so[((size_t)bh*LL + lr4.y)*DH + fr] = (_Float16)oacc[1];
        so[((size_t)bh*LL + lr4.z)*DH + fr] = (_Float16)oacc[2];
        so[((size_t)bh*LL + lr4.w)*DH + fr] = (_Float16)oacc[3];
    }
}

// ---------------- fused round-combine + Wo(fp16 MFMA) + residual + LN2 + FFN ----------------
__global__ __launch_bounds__(256, 3)
void k_out_ffn(const _Float16* __restrict__ so, const float* __restrict__ slog,
               const _Float16* __restrict__ WoT, const float* __restrict__ lng,
               const float* __restrict__ lnb, const unsigned short* __restrict__ W1T,
               const float* __restrict__ b1, const unsigned short* __restrict__ W2T,
               const float* __restrict__ b2, float* __restrict__ h) {
    __shared__ float hs[16][128];                             // 8 KB (h + Wo out)
    __shared__ __align__(16) _Float16 At[16][136];            // combine out, fp16
    __shared__ __align__(16) unsigned short Albf[16][136];    // LN2 out, bf16
    __shared__ __align__(16) unsigned short albf[16][520];    // gelu acts, bf16
    int row0 = blockIdx.x * 16;
    int t = threadIdx.x;               // 256
    int b = row0 / SS;
    int s0 = row0 & (SS-1);

    // stage h rows
    {
        const float4* src = (const float4*)(h + (size_t)row0*DD);
        float4* dst = (float4*)&hs[0][0];
        dst[t]       = src[t];
        dst[t + 256] = src[t + 256];
    }
    // combine over hash rounds: sum unnormalized o, scale by exp(-m)/S
    {
        int half = t & 1, task = t >> 1;
        int r = task >> 3, h_ = task & 7;
        int s = s0 + r;
        int bh = b*HH + h_;
        const float* sl = slog + (size_t)bh*LL + s;
        float lg[NHASH];
        float m = -3.4e38f;
        #pragma unroll
        for (int n = 0; n < NHASH; n++) {
            lg[n] = sl[n*SS];
            m = fmaxf(m, lg[n]);
        }
        float S = 0.f;
        #pragma unroll
        for (int n = 0; n < NHASH; n++) S += __expf(lg[n] - m);
        float scale = __expf(-m) / S;
        float o[8] = {0,0,0,0,0,0,0,0};
        #pragma unroll
        for (int n = 0; n < NHASH; n++) {
            const f16x8* sp = (const f16x8*)(so + ((size_t)bh*LL + n*SS + s)*DH + half*8);
            f16x8 a = *sp;
            #pragma unroll
            for (int j = 0; j < 8; j++) o[j] += (float)a[j];
        }
        f16x8 ov;
        #pragma unroll
        for (int j = 0; j < 8; j++) ov[j] = (_Float16)(o[j] * scale);
        *(f16x8*)&At[r][h_*16 + half*8] = ov;
    }
    __syncthreads();

    int w = t >> 6, lane = t & 63;
    int fr = lane & 15, kg = lane >> 4;

    // Wo MFMA: wave w computes D[16 x 32] at cols w*32
    {
        f32x4 ao[2];
        ao[0] = (f32x4){0.f,0.f,0.f,0.f}; ao[1] = (f32x4){0.f,0.f,0.f,0.f};
        #pragma unroll
        for (int ks = 0; ks < 4; ks++) {
            f16x8 af = *(const f16x8*)&At[fr][ks*32 + kg*8];
            #pragma unroll
            for (int nt = 0; nt < 2; nt++) {
                const _Float16* bp = WoT + (size_t)(w*32 + nt*16 + fr)*128 + ks*32 + kg*8;
                f16x8 bf = *(const f16x8*)bp;
                ao[nt] = __builtin_amdgcn_mfma_f32_16x16x32_f16(af, bf, ao[nt], 0, 0, 0);
            }
        }
        #pragma unroll
        for (int nt = 0; nt < 2; nt++)
            #pragma unroll
            for (int i = 0; i < 4; i++)
                hs[kg*4 + i][w*32 + nt*16 + fr] += ao[nt][i];
    }
    __syncthreads();

    // LN2 from hs -> Albf (bf16)
    {
        int r = t >> 4, sub = t & 15;
        float4 xa = *(const float4*)&hs[r][sub*8];
        float4 xb = *(const float4*)&hs[r][sub*8 + 4];
        float s = xa.x+xa.y+xa.z+xa.w + xb.x+xb.y+xb.z+xb.w;
        s += __shfl_xor(s,1); s += __shfl_xor(s,2);
        s += __shfl_xor(s,4); s += __shfl_xor(s,8);
        float m = s * (1.0f/128.0f);
        float d0=xa.x-m, d1=xa.y-m, d2=xa.z-m, d3=xa.w-m;
        float d4=xb.x-m, d5=xb.y-m, d6=xb.z-m, d7=xb.w-m;
        float vs = d0*d0+d1*d1+d2*d2+d3*d3+d4*d4+d5*d5+d6*d6+d7*d7;
        vs += __shfl_xor(vs,1); vs += __shfl_xor(vs,2);
        vs += __shfl_xor(vs,4); vs += __shfl_xor(vs,8);
        float inv = 1.0f / sqrtf(vs * (1.0f/128.0f) + 1e-5f);
        float4 ga = *(const float4*)&lng[sub*8], gb = *(const float4*)&lng[sub*8+4];
        float4 ba = *(const float4*)&lnb[sub*8], bb = *(const float4*)&lnb[sub*8+4];
        bf16x8 vv;
        vv[0] = (short)f2bf(d0*inv*ga.x + ba.x);
        vv[1] = (short)f2bf(d1*inv*ga.y + ba.y);
        vv[2] = (short)f2bf(d2*inv*ga.z + ba.z);
        vv[3] = (short)f2bf(d3*inv*ga.w + ba.w);
        vv[4] = (short)f2bf(d4*inv*gb.x + bb.x);
        vv[5] = (short)f2bf(d5*inv*gb.y + bb.y);
        vv[6] = (short)f2bf(d6*inv*gb.z + bb.z);
        vv[7] = (short)f2bf(d7*inv*gb.w + bb.w);
        *(bf16x8*)&Albf[r][sub*8] = vv;
    }
    __syncthreads();

    // FF1: each wave computes C1[16 x 128] at cols w*128
    f32x4 acc1[8];
    #pragma unroll
    for (int i = 0; i < 8; i++) acc1[i] = (f32x4){0.f, 0.f, 0.f, 0.f};
    {
        const unsigned short* w1p = W1T + (size_t)(w*128 + fr)*128 + kg*8;
        #pragma unroll
        for (int ks = 0; ks < 4; ks++) {
            bf16x8 af = *(const bf16x8*)&Albf[fr][ks*32 + kg*8];
            #pragma unroll
            for (int nt = 0; nt < 8; nt++) {
                bf16x8 bf = *(const bf16x8*)(w1p + nt*16*128 + ks*32);
                acc1[nt] = __builtin_amdgcn_mfma_f32_16x16x32_bf16(af, bf, acc1[nt], 0, 0, 0);
            }
        }
    }
    // bias + GELU -> bf16 activations
    #pragma unroll
    for (int nt = 0; nt < 8; nt++) {
        int col = w*128 + nt*16 + fr;
        float bias = b1[col];
        #pragma unroll
        for (int i = 0; i < 4; i++) {
            int row = kg*4 + i;
            float x = acc1[nt][i] + bias;
            float t0 = tanhf(0.7978845608028654f * (x + 0.044715f*x*x*x));
            albf[row][col] = f2bf(0.5f*x*(1.0f + t0));
        }
    }
    __syncthreads();

    // FF2: each wave computes D2[16 x 32] at cols w*32; write h = hs + D2 + b2
    f32x4 acc2[2];
    acc2[0] = (f32x4){0.f,0.f,0.f,0.f};
    acc2[1] = (f32x4){0.f,0.f,0.f,0.f};
    {
        const unsigned short* w2p = W2T + (size_t)(w*32 + fr)*512 + kg*8;
        #pragma unroll
        for (int ks = 0; ks < 16; ks++) {
            bf16x8 af = *(const bf16x8*)&albf[fr][ks*32 + kg*8];
            bf16x8 b0 = *(const bf16x8*)(w2p + ks*32);
            bf16x8 b1f = *(const bf16x8*)(w2p + 16*512 + ks*32);
            acc2[0] = __builtin_amdgcn_mfma_f32_16x16x32_bf16(af, b0, acc2[0], 0, 0, 0);
            acc2[1] = __builtin_amdgcn_mfma_f32_16x16x32_bf16(af, b1f, acc2[1], 0, 0, 0);
        }
    }
    #pragma unroll
    for (int nt = 0; nt < 2; nt++) {
        int col = w*32 + nt*16 + fr;
        float bias = b2[col];
        #pragma unroll
        for (int i = 0; i < 4; i++) {
            int row = kg*4 + i;
            h[(size_t)(row0 + row)*DD + col] = hs[row][col] + acc2[nt][i] + bias;
        }
    }
}

// ---------------- two-stage pool ----------------
__global__ void k_pool(const float* __restrict__ h, float* __restrict__ partial) {
    int blk = blockIdx.x;              // b*64 + c
    int t = threadIdx.x;               // 128
    int b = blk >> 6, c = blk & 63;
    const float* hp = h + ((size_t)b*SS + c*32)*DD + t;
    float acc = 0.f;
    #pragma unroll
    for (int i = 0; i < 32; i++) acc += hp[i*DD];
    partial[blk*DD + t] = acc;
}

__global__ void k_final(const float* __restrict__ partial, const float* __restrict__ fcW,
                        const float* __restrict__ fcb, float* __restrict__ out) {
    __shared__ float red[4];
    int b = blockIdx.x, t = threadIdx.x;   // 128 threads
    const float* pp = partial + (size_t)b*64*DD + t;
    float acc = 0.f;
    #pragma unroll
    for (int c = 0; c < 64; c++) acc += pp[c*DD];
    float pooled = acc * (1.0f/(float)SS);
    float p0 = pooled * fcW[t*2+0];
    float p1 = pooled * fcW[t*2+1];
    #pragma unroll
    for (int o = 32; o >= 1; o >>= 1) { p0 += __shfl_xor(p0,o); p1 += __shfl_xor(p1,o); }
    int w = t >> 6;
    if ((t & 63) == 0) { red[w*2] = p0; red[w*2+1] = p1; }
    __syncthreads();
    if (t == 0) {
        out[b*2 + 0] = red[0] + red[2] + fcb[0];
        out[b*2 + 1] = red[1] + red[3] + fcb[1];
    }
}

extern "C" void kernel_launch(void* const* d_in, const int* in_sizes, int n_in,
                              void* d_out, int out_size, void* d_ws, size_t ws_size,
                              hipStream_t stream) {
    const float* x    = (const float*)d_in[0];
    const float* embW = (const float*)d_in[1];
    const float* embB = (const float*)d_in[2];
    const float* Wqk  = (const float*)d_in[3];
    const float* Wv   = (const float*)d_in[4];
    const float* Wo   = (const float*)d_in[5];
    const float* R    = (const float*)d_in[6];
    const float* ln1g = (const float*)d_in[7];
    const float* ln1b = (const float*)d_in[8];
    const float* ln2g = (const float*)d_in[9];
    const float* ln2b = (const float*)d_in[10];
    const float* W1   = (const float*)d_in[11];
    const float* b1   = (const float*)d_in[12];
    const float* W2   = (const float*)d_in[13];
    const float* b2   = (const float*)d_in[14];
    const float* fcW  = (const float*)d_in[15];
    const float* fcb  = (const float*)d_in[16];
    float* out = (float*)d_out;

    char* w = (char*)d_ws;
    auto carve = [&](size_t bytes) -> char* {
        char* p = w;
        w += (bytes + 255) & ~(size_t)255;
        return p;
    };
    float* h       = (float*)carve((size_t)BB*SS*DD*4);
    _Float16* kn16 = (_Float16*)carve((size_t)NBH*SS*DH*2);
    _Float16* v16  = (_Float16*)carve((size_t)NBH*SS*DH*2);
    float* nrmg    = (float*)carve((size_t)NBH*SS*4);
    int*   bkt     = (int*)  carve((size_t)NBH*LL*4);
    int*   sticker = (int*)  carve((size_t)NBH*LL*4);
    _Float16* so   = (_Float16*)carve((size_t)NBH*LL*DH*2);
    float* slog    = (float*)carve((size_t)NBH*LL*4);
    float* partial = (float*)carve((size_t)BB*64*DD*4);
    unsigned short* w1t = (unsigned short*)carve((size_t)DEPTH*DD*DFF*2);
    unsigned short* w2t = (unsigned short*)carve((size_t)DEPTH*DFF*DD*2);
    _Float16* wqk16 = (_Float16*)carve((size_t)DEPTH*DD*DD*2);
    _Float16* wv16  = (_Float16*)carve((size_t)DEPTH*DD*DD*2);
    _Float16* wo16  = (_Float16*)carve((size_t)DEPTH*DD*DD*2);

    // one-time per call: transpose + cast weights (all layers)
    k_wcast<<<dim3(DFF/32, DD/32, DEPTH), dim3(32, 8), 0, stream>>>(W1, w1t, DD, DFF);
    k_wcast<<<dim3(DD/32, DFF/32, DEPTH), dim3(32, 8), 0, stream>>>(W2, w2t, DFF, DD);
    k_wcast16<<<dim3(DD/32, DD/32, DEPTH), dim3(32, 8), 0, stream>>>(Wqk, wqk16, DD, DD);
    k_wcast16<<<dim3(DD/32, DD/32, DEPTH), dim3(32, 8), 0, stream>>>(Wv, wv16, DD, DD);
    k_wcast16<<<dim3(DD/32, DD/32, DEPTH), dim3(32, 8), 0, stream>>>(Wo, wo16, DD, DD);

    k_embed<<<(BB*SS*DD)/256, 256, 0, stream>>>(x, embW, embB, h);

    for (int l = 0; l < DEPTH; l++) {
        const _Float16* wqkl = wqk16 + (size_t)l*DD*DD;
        const _Float16* wvl  = wv16  + (size_t)l*DD*DD;
        const _Float16* wol  = wo16  + (size_t)l*DD*DD;
        const float* rl  = R   + (size_t)l*HH*DH*NHASH*16;
        const float* g1  = ln1g + l*DD; const float* bg1 = ln1b + l*DD;
        const float* g2  = ln2g + l*DD; const float* bg2 = ln2b + l*DD;
        const unsigned short* w1l = w1t + (size_t)l*DD*DFF;
        const unsigned short* w2l = w2t + (size_t)l*DFF*DD;
        const float* bb1 = b1 + l*DFF;
        const float* bb2 = b2 + l*DD;

        k_proj_qkv<<<(BB*SS)/16, 256, 0, stream>>>(h, g1, bg1, wqkl, wvl,
                                                   kn16, v16, nrmg);
        k_hash<<<(NBH*NHASH*SS)/256, 256, 0, stream>>>(kn16, rl, bkt);
        k_scatter<<<NBH*NHASH, 256, 0, stream>>>(bkt, sticker);
        k_attn<<<NBH*NCHUNK, 256, 0, stream>>>(kn16, v16, nrmg, sticker, so, slog);
        k_out_ffn<<<(BB*SS)/16, 256, 0, stream>>>(so, slog, wol, g2, bg2,
                                                  w1l, bb1, w2l, bb2, h);
    }

    k_pool<<<BB*64, 128, 0, stream>>>(h, partial);
    k_final<<<BB, 128, 0, stream>>>(partial, fcW, fcb, out);
}

// Round 17
// 508.784 us; speedup vs baseline: 1.6625x; 1.6625x over previous
//
#include <hip/hip_runtime.h>
#include <math.h>

#define BB 4
#define SS 2048
#define INDIM 4
#define DD 128
#define HH 8
#define DH 16
#define DEPTH 6
#define BUCKET 64
#define NHASH 8
#define NBK 32                 // buckets per hash round
#define DFF 512
#define LL (NHASH*SS)          // 16384 per (b,h)
#define NCHUNK (NHASH*NBK)     // 256 chunks per (b,h)
#define NBH (BB*HH)            // 32

typedef short bf16x8 __attribute__((ext_vector_type(8)));
typedef _Float16 f16x8 __attribute__((ext_vector_type(8)));
typedef _Float16 f16x2 __attribute__((ext_vector_type(2)));
typedef float f32x4 __attribute__((ext_vector_type(4)));

__device__ __forceinline__ unsigned short f2bf(float f) {
    unsigned u = __builtin_bit_cast(unsigned, f);
    unsigned r = u + 0x7FFFu + ((u >> 16) & 1u);   // RTNE
    return (unsigned short)(r >> 16);
}

// ---------------- embedding: h = x @ embW + embb ----------------
__global__ void k_embed(const float* __restrict__ x, const float* __restrict__ W,
                        const float* __restrict__ b, float* __restrict__ h) {
    int idx = blockIdx.x * blockDim.x + threadIdx.x;   // B*S*D
    if (idx >= BB*SS*DD) return;
    int d = idx % DD, bs = idx / DD;
    const float* xr = x + bs*INDIM;
    float acc = b[d];
    #pragma unroll
    for (int k = 0; k < INDIM; k++) acc += xr[k] * W[k*DD + d];
    h[idx] = acc;
}

// ---------------- weight transpose + bf16 cast: dst[c][r] = bf16(src[r][c]) ----------------
__global__ void k_wcast(const float* __restrict__ src, unsigned short* __restrict__ dst,
                        int R, int C) {
    __shared__ float tile[32][33];
    int l = blockIdx.z;
    const float* s = src + (size_t)l*R*C;
    unsigned short* d = dst + (size_t)l*R*C;
    int c0 = blockIdx.x*32, r0 = blockIdx.y*32;
    int tx = threadIdx.x, ty = threadIdx.y;   // 32 x 8
    #pragma unroll
    for (int i = 0; i < 4; i++)
        tile[ty + i*8][tx] = s[(size_t)(r0 + ty + i*8)*C + c0 + tx];
    __syncthreads();
    #pragma unroll
    for (int i = 0; i < 4; i++)
        d[(size_t)(c0 + ty + i*8)*R + r0 + tx] = f2bf(tile[tx][ty + i*8]);
}

// ---------------- weight transpose + fp16 cast ----------------
__global__ void k_wcast16(const float* __restrict__ src, _Float16* __restrict__ dst,
                          int R, int C) {
    __shared__ float tile[32][33];
    int l = blockIdx.z;
    const float* s = src + (size_t)l*R*C;
    _Float16* d = dst + (size_t)l*R*C;
    int c0 = blockIdx.x*32, r0 = blockIdx.y*32;
    int tx = threadIdx.x, ty = threadIdx.y;   // 32 x 8
    #pragma unroll
    for (int i = 0; i < 4; i++)
        tile[ty + i*8][tx] = s[(size_t)(r0 + ty + i*8)*C + c0 + tx];
    __syncthreads();
    #pragma unroll
    for (int i = 0; i < 4; i++)
        d[(size_t)(c0 + ty + i*8)*R + r0 + tx] = (_Float16)tile[tx][ty + i*8];
}

// ---------------- fused LN1 + qk/v projections: fp16 MFMA, 16 rows/block ----------------
// Outputs fp32 qk (for the hash, bit-exact), plus attention-ready operands:
// kn16 = normalized K (fp16), v16 (fp16), nrm = |q|*0.25*log2e (fp32).
__global__ __launch_bounds__(256, 4)
void k_proj_qkv(const float* __restrict__ hin, const float* __restrict__ lng,
                const float* __restrict__ lnb, const _Float16* __restrict__ WqkT,
                const _Float16* __restrict__ WvT, float* __restrict__ qk,
                _Float16* __restrict__ kn16, _Float16* __restrict__ v16,
                float* __restrict__ nrmg) {
    __shared__ float A[16][128];
    __shared__ __align__(16) _Float16 Lf[16][136];
    int row0 = blockIdx.x * 16;
    int t = threadIdx.x;                  // 256
    {
        const float4* src = (const float4*)(hin + (size_t)row0*DD);
        float4* dst = (float4*)&A[0][0];
        dst[t]       = src[t];
        dst[t + 256] = src[t + 256];
    }
    __syncthreads();
    // layernorm: 16 threads per row, 8 elems each -> fp16 tile
    {
        int r = t >> 4, sub = t & 15;
        float4 xa = *(const float4*)&A[r][sub*8];
        float4 xb = *(const float4*)&A[r][sub*8 + 4];
        float s = xa.x+xa.y+xa.z+xa.w + xb.x+xb.y+xb.z+xb.w;
        s += __shfl_xor(s,1); s += __shfl_xor(s,2);
        s += __shfl_xor(s,4); s += __shfl_xor(s,8);
        float m = s * (1.0f/128.0f);
        float d0=xa.x-m, d1=xa.y-m, d2=xa.z-m, d3=xa.w-m;
        float d4=xb.x-m, d5=xb.y-m, d6=xb.z-m, d7=xb.w-m;
        float vs = d0*d0+d1*d1+d2*d2+d3*d3+d4*d4+d5*d5+d6*d6+d7*d7;
        vs += __shfl_xor(vs,1); vs += __shfl_xor(vs,2);
        vs += __shfl_xor(vs,4); vs += __shfl_xor(vs,8);
        float inv = 1.0f / sqrtf(vs * (1.0f/128.0f) + 1e-5f);
        float4 ga = *(const float4*)&lng[sub*8], gb = *(const float4*)&lng[sub*8+4];
        float4 ba = *(const float4*)&lnb[sub*8], bb = *(const float4*)&lnb[sub*8+4];
        f16x8 vv;
        vv[0] = (_Float16)(d0*inv*ga.x + ba.x);
        vv[1] = (_Float16)(d1*inv*ga.y + ba.y);
        vv[2] = (_Float16)(d2*inv*ga.z + ba.z);
        vv[3] = (_Float16)(d3*inv*ga.w + ba.w);
        vv[4] = (_Float16)(d4*inv*gb.x + bb.x);
        vv[5] = (_Float16)(d5*inv*gb.y + bb.y);
        vv[6] = (_Float16)(d6*inv*gb.z + bb.z);
        vv[7] = (_Float16)(d7*inv*gb.w + bb.w);
        *(f16x8*)&Lf[r][sub*8] = vv;
    }
    __syncthreads();
    int w = t >> 6, lane = t & 63;
    int fr = lane & 15, kg = lane >> 4;
    f32x4 aq[2], av[2];
    aq[0] = (f32x4){0.f,0.f,0.f,0.f}; aq[1] = (f32x4){0.f,0.f,0.f,0.f};
    av[0] = (f32x4){0.f,0.f,0.f,0.f}; av[1] = (f32x4){0.f,0.f,0.f,0.f};
    #pragma unroll
    for (int ks = 0; ks < 4; ks++) {
        f16x8 af = *(const f16x8*)&Lf[fr][ks*32 + kg*8];
        #pragma unroll
        for (int nt = 0; nt < 2; nt++) {
            const _Float16* bp = WqkT + (size_t)(w*32 + nt*16 + fr)*128 + ks*32 + kg*8;
            f16x8 bq = *(const f16x8*)bp;
            aq[nt] = __builtin_amdgcn_mfma_f32_16x16x32_f16(af, bq, aq[nt], 0, 0, 0);
            const _Float16* vp = WvT + (size_t)(w*32 + nt*16 + fr)*128 + ks*32 + kg*8;
            f16x8 bv = *(const f16x8*)vp;
            av[nt] = __builtin_amdgcn_mfma_f32_16x16x32_f16(af, bv, av[nt], 0, 0, 0);
        }
    }
    int b = row0 / SS;
    int sb = row0 & (SS-1);
    #pragma unroll
    for (int nt = 0; nt < 2; nt++) {
        int n = w*32 + nt*16 + fr;
        int h_ = n >> 4, d_ = n & 15;   // d_ == fr
        // per-row |q|^2 over the head's 16 dims (lanes fr=0..15 of this group)
        float ssq[4];
        #pragma unroll
        for (int i = 0; i < 4; i++) { float xx = aq[nt][i]; ssq[i] = xx*xx; }
        #pragma unroll
        for (int o = 1; o <= 8; o <<= 1) {
            #pragma unroll
            for (int i = 0; i < 4; i++) ssq[i] += __shfl_xor(ssq[i], o);
        }
        #pragma unroll
        for (int i = 0; i < 4; i++) {
            int s = sb + kg*4 + i;
            size_t rowi = ((size_t)(b*HH + h_))*SS + s;
            qk[rowi*DH + d_] = aq[nt][i];
            float nn = sqrtf(ssq[i]);
            float inv = 1.0f / nn;
            kn16[rowi*DH + d_] = (_Float16)(aq[nt][i] * inv);
            v16[rowi*DH + d_]  = (_Float16)(av[nt][i]);
            if (d_ == 0) nrmg[rowi] = nn * 0.25f * 1.4426950408889634f;
        }
    }
}

// ---------------- LSH hashing: 2048 blocks, one position per thread (fp32 qk) ----------------
__global__ void k_hash(const float* __restrict__ qk, const float* __restrict__ R,
                       int* __restrict__ bkt) {
    __shared__ float Rs[256];             // R[h_][d][n][r] for block-uniform (h_,n)
    int idx = blockIdx.x*256 + threadIdx.x;   // [bh][n][s]
    int s = idx & (SS-1); int t2 = idx >> 11;
    int n = t2 & 7; int bh = t2 >> 3; int h_ = bh & 7;
    {
        int tt = threadIdx.x;
        int d = tt >> 4, r = tt & 15;
        Rs[tt] = R[(((h_*DH + d)*NHASH + n)*16) + r];
    }
    __syncthreads();
    const float4* q4 = (const float4*)(qk + ((size_t)bh*SS + s)*DH);
    float4 q0 = q4[0], q1 = q4[1], q2 = q4[2], q3 = q4[3];
    float rxv[16];
    #pragma unroll
    for (int r = 0; r < 16; r++) {
        rxv[r] = q0.x*Rs[  0+r] + q0.y*Rs[ 16+r] + q0.z*Rs[ 32+r] + q0.w*Rs[ 48+r]
               + q1.x*Rs[ 64+r] + q1.y*Rs[ 80+r] + q1.z*Rs[ 96+r] + q1.w*Rs[112+r]
               + q2.x*Rs[128+r] + q2.y*Rs[144+r] + q2.z*Rs[160+r] + q2.w*Rs[176+r]
               + q3.x*Rs[192+r] + q3.y*Rs[208+r] + q3.z*Rs[224+r] + q3.w*Rs[240+r];
    }
    float best = rxv[0]; int bi = 0;
    #pragma unroll
    for (int jx = 1; jx < 16; jx++) if (rxv[jx]  > best) { best = rxv[jx];  bi = jx; }
    #pragma unroll
    for (int jx = 0; jx < 16; jx++) if (-rxv[jx] > best) { best = -rxv[jx]; bi = 16 + jx; }
    bkt[idx] = n*NBK + bi;
}

// ---------------- counting sort per (b,h,round) ----------------
__global__ void k_scatter(const int* __restrict__ bkt, int* __restrict__ sticker) {
    __shared__ int hist[256*33];       // padded stride 33: conflict-free columns
    __shared__ int cs[8*33];
    __shared__ int bbk[NBK];
    int blk = blockIdx.x;              // B*H*NHASH
    int n = blk & 7, bh = blk >> 3;
    int t = threadIdx.x;               // 256 threads, 8 consecutive elems each
    #pragma unroll
    for (int k = 0; k < NBK; k++) hist[t*33 + k] = 0;
    const int* bp = bkt + (size_t)bh*LL + n*SS;
    int local[8];
    #pragma unroll
    for (int e = 0; e < 8; e++) {
        int k = bp[t*8 + e] - n*NBK;
        local[e] = k;
        hist[t*33 + k]++;
    }
    __syncthreads();
    {
        int i = t >> 5, k = t & 31;
        int ssum = 0;
        #pragma unroll
        for (int rr = 0; rr < 32; rr++) ssum += hist[(i*32+rr)*33 + k];
        cs[i*33 + k] = ssum;
    }
    __syncthreads();
    if (t < 32) {
        int tot = 0;
        #pragma unroll
        for (int i = 0; i < 8; i++) tot += cs[i*33 + t];
        int x = tot;
        #pragma unroll
        for (int o = 1; o < 32; o <<= 1) {
            int y = __shfl(x, (t >= o) ? (t - o) : 0, 64);
            if (t >= o) x += y;
        }
        bbk[t] = n*SS + x - tot;        // exclusive prefix + round base
    }
    __syncthreads();
    {
        int i = t >> 5, k = t & 31;
        int run = bbk[k];
        for (int ii = 0; ii < i; ii++) run += cs[ii*33 + k];
        for (int rr = 0; rr < 32; rr++) {
            int idx = (i*32+rr)*33 + k;
            int c0 = hist[idx];
            hist[idx] = run;
            run += c0;
        }
    }
    __syncthreads();
    #pragma unroll
    for (int e = 0; e < 8; e++) {
        int k = local[e];
        int pos = hist[t*33 + k]++;
        sticker[(size_t)bh*LL + pos] = n*SS + t*8 + e;
    }
}

// ---------------- chunked look-back attention, fp16 MFMA (transposed QK) ----------------
// Kf stores only the 16 real dims ([128][24], 6KB); the K=32 MFMA's upper-half
// fragments are zero REGISTERS (kg>=2 lanes), not LDS. 28.25KB LDS -> 5 blocks/CU.
__global__ __launch_bounds__(256, 5)
void k_attn(const _Float16* __restrict__ kn16, const _Float16* __restrict__ v16,
            const float* __restrict__ nrmg, const int* __restrict__ sticker,
            _Float16* __restrict__ so, float* __restrict__ slog) {
    __shared__ __align__(16) char smem[28928];
    _Float16 (*Kf)[24]  = (_Float16(*)[24])smem;              // 128x24  = 6144
    _Float16 (*P)[136]  = (_Float16(*)[136])(smem + 6144);    // 64x136  = 17408 [q][j]
    _Float16 (*VT)[136] = (_Float16(*)[136])(smem + 23552);   // 16x136  = 4352
    int*   pk   = (int*)(smem + 27904);                       // 128 ints
    float* nrm  = (float*)(smem + 28416);                     // 64 floats (|k|*0.25*log2e)
    int*   lraw = (int*)(smem + 28672);                       // 64 ints

    int blk = blockIdx.x;              // B*H*NCHUNK
    int c = blk & (NCHUNK-1), bh = blk >> 8;
    int t = threadIdx.x;
    const int* stk = sticker + (size_t)bh*LL;

    // ---- stage: 32B fp16 loads, zero arithmetic ----
    if (t < 128) {
        int j = t;
        int cc = (j < 64) ? c : ((c + NCHUNK - 1) & (NCHUNK-1));
        int raw = stk[cc*BUCKET + (j & 63)];
        int sk = raw & (SS-1);
        const f16x8* kp = (const f16x8*)(kn16 + ((size_t)bh*SS + sk)*DH);
        *(f16x8*)&Kf[j][0] = kp[0];
        *(f16x8*)&Kf[j][8] = kp[1];
        pk[j] = sk;
        if (j < 64) { nrm[j] = nrmg[(size_t)bh*SS + sk]; lraw[j] = raw; }
    } else {
        int j = t - 128;
        int cc = (j < 64) ? c : ((c + NCHUNK - 1) & (NCHUNK-1));
        int sk = stk[cc*BUCKET + (j & 63)] & (SS-1);
        const f16x8* vp = (const f16x8*)(v16 + ((size_t)bh*SS + sk)*DH);
        f16x8 v0 = vp[0], v1 = vp[1];
        VT[ 0][j]=v0[0]; VT[ 1][j]=v0[1]; VT[ 2][j]=v0[2]; VT[ 3][j]=v0[3];
        VT[ 4][j]=v0[4]; VT[ 5][j]=v0[5]; VT[ 6][j]=v0[6]; VT[ 7][j]=v0[7];
        VT[ 8][j]=v1[0]; VT[ 9][j]=v1[1]; VT[10][j]=v1[2]; VT[11][j]=v1[3];
        VT[12][j]=v1[4]; VT[13][j]=v1[5]; VT[14][j]=v1[6]; VT[15][j]=v1[7];
    }
    __syncthreads();

    int w = t >> 6, lane = t & 63;
    int fr = lane & 15, kg = lane >> 4;
    int qrow = w*16 + fr;

    // ---- QK^T transposed: acc[nt] holds S^T[j=nt*16+kg*4+i][q=w*16+fr] ----
    f32x4 acc[8];
    #pragma unroll
    for (int nt = 0; nt < 8; nt++) acc[nt] = (f32x4){0.f,0.f,0.f,0.f};
    {
        f16x8 z = {0,0,0,0,0,0,0,0};
        f16x8 bq = z;
        if (kg < 2) {
            f16x8 kfq = *(const f16x8*)&Kf[qrow][kg*8];
            _Float16 qs = (_Float16)nrm[qrow];
            bq = kfq * qs;                       // B operand: Q (log2-scaled)
        }
        #pragma unroll
        for (int nt = 0; nt < 8; nt++) {
            f16x8 afk = z;
            if (kg < 2) afk = *(const f16x8*)&Kf[nt*16 + fr][kg*8];  // A: K rows
            acc[nt] = __builtin_amdgcn_mfma_f32_16x16x32_f16(afk, bq, acc[nt], 0, 0, 0);
        }
    }
    // ---- mask + exp2 -> packed P[q][j] (same-wave rows), sum over j local ----
    int pq_self = pk[qrow];
    float s = 0.f;
    #pragma unroll
    for (int nt = 0; nt < 8; nt++) {
        int4 pk4 = *(const int4*)&pk[nt*16 + kg*4];
        float d0 = (pk4.x == pq_self) ? -5e4f : acc[nt][0];
        float d1 = (pk4.y == pq_self) ? -5e4f : acc[nt][1];
        float d2 = (pk4.z == pq_self) ? -5e4f : acc[nt][2];
        float d3 = (pk4.w == pq_self) ? -5e4f : acc[nt][3];
        float p0 = exp2f(d0), p1 = exp2f(d1), p2 = exp2f(d2), p3 = exp2f(d3);
        s += (p0 + p1) + (p2 + p3);
        f16x2 w0 = {(_Float16)p0, (_Float16)p1};
        f16x2 w1 = {(_Float16)p2, (_Float16)p3};
        *(f16x2*)&P[qrow][nt*16 + kg*4]     = w0;
        *(f16x2*)&P[qrow][nt*16 + kg*4 + 2] = w1;
    }
    s += __shfl_xor(s, 16);
    s += __shfl_xor(s, 32);
    if (kg == 0) slog[(size_t)bh*LL + lraw[qrow]] = __logf(s);
    // no barrier: P rows for wave w written and read by wave w only

    // ---- PV: wave w computes rows w*16..+15 x 16 dims (unnormalized) ----
    f32x4 oacc = (f32x4){0.f,0.f,0.f,0.f};
    #pragma unroll
    for (int ks = 0; ks < 4; ks++) {
        f16x8 af = *(const f16x8*)&P[w*16 + fr][ks*32 + kg*8];
        f16x8 bf = *(const f16x8*)&VT[fr][ks*32 + kg*8];
        oacc = __builtin_amdgcn_mfma_f32_16x16x32_f16(af, bf, oacc, 0, 0, 0);
    }
    // ---- scatter-write unnormalized o (unsorted order, fp16) ----
    {
        int4 lr4 = *(const int4*)&lraw[w*16 + kg*4];
        so[((size_t)bh*LL + lr4.x)*DH + fr] = (_Float16)oacc[0];
        so[((size_t)bh*LL + lr4.y)*DH + fr] = (_Float16)oacc[1];
        so[((size_t)bh*LL + lr4.z)*DH + fr] = (_Float16)oacc[2];
        so[((size_t)bh*LL + lr4.w)*DH + fr] = (_Float16)oacc[3];
    }
}

// ---------------- fused round-combine + Wo(fp16 MFMA) + residual + LN2 + FFN ----------------
__global__ __launch_bounds__(256, 3)
void k_out_ffn(const _Float16* __restrict__ so, const float* __restrict__ slog,
               const _Float16* __restrict__ WoT, const float* __restrict__ lng,
               const float* __restrict__ lnb, const unsigned short* __restrict__ W1T,
               const float* __restrict__ b1, const unsigned short* __restrict__ W2T,
               const float* __restrict__ b2, float* __restrict__ h) {
    __shared__ float hs[16][128];                             // 8 KB (h + Wo out)
    __shared__ __align__(16) _Float16 At[16][136];            // combine out, fp16
    __shared__ __align__(16) unsigned short Albf[16][136];    // LN2 out, bf16
    __shared__ __align__(16) unsigned short albf[16][520];    // gelu acts, bf16
    int row0 = blockIdx.x * 16;
    int t = threadIdx.x;               // 256
    int b = row0 / SS;
    int s0 = row0 & (SS-1);

    // stage h rows
    {
        const float4* src = (const float4*)(h + (size_t)row0*DD);
        float4* dst = (float4*)&hs[0][0];
        dst[t]       = src[t];
        dst[t + 256] = src[t + 256];
    }
    // combine over hash rounds: sum unnormalized o, scale by exp(-m)/S
    {
        int half = t & 1, task = t >> 1;
        int r = task >> 3, h_ = task & 7;
        int s = s0 + r;
        int bh = b*HH + h_;
        const float* sl = slog + (size_t)bh*LL + s;
        float lg[NHASH];
        float m = -3.4e38f;
        #pragma unroll
        for (int n = 0; n < NHASH; n++) {
            lg[n] = sl[n*SS];
            m = fmaxf(m, lg[n]);
        }
        float S = 0.f;
        #pragma unroll
        for (int n = 0; n < NHASH; n++) S += __expf(lg[n] - m);
        float scale = __expf(-m) / S;
        float o[8] = {0,0,0,0,0,0,0,0};
        #pragma unroll
        for (int n = 0; n < NHASH; n++) {
            const f16x8* sp = (const f16x8*)(so + ((size_t)bh*LL + n*SS + s)*DH + half*8);
            f16x8 a = *sp;
            #pragma unroll
            for (int j = 0; j < 8; j++) o[j] += (float)a[j];
        }
        f16x8 ov;
        #pragma unroll
        for (int j = 0; j < 8; j++) ov[j] = (_Float16)(o[j] * scale);
        *(f16x8*)&At[r][h_*16 + half*8] = ov;
    }
    __syncthreads();

    int w = t >> 6, lane = t & 63;
    int fr = lane & 15, kg = lane >> 4;

    // Wo MFMA: wave w computes D[16 x 32] at cols w*32
    {
        f32x4 ao[2];
        ao[0] = (f32x4){0.f,0.f,0.f,0.f}; ao[1] = (f32x4){0.f,0.f,0.f,0.f};
        #pragma unroll
        for (int ks = 0; ks < 4; ks++) {
            f16x8 af = *(const f16x8*)&At[fr][ks*32 + kg*8];
            #pragma unroll
            for (int nt = 0; nt < 2; nt++) {
                const _Float16* bp = WoT + (size_t)(w*32 + nt*16 + fr)*128 + ks*32 + kg*8;
                f16x8 bf = *(const f16x8*)bp;
                ao[nt] = __builtin_amdgcn_mfma_f32_16x16x32_f16(af, bf, ao[nt], 0, 0, 0);
            }
        }
        #pragma unroll
        for (int nt = 0; nt < 2; nt++)
            #pragma unroll
            for (int i = 0; i < 4; i++)
                hs[kg*4 + i][w*32 + nt*16 + fr] += ao[nt][i];
    }
    __syncthreads();

    // LN2 from hs -> Albf (bf16)
    {
        int r = t >> 4, sub = t & 15;
        float4 xa = *(const float4*)&hs[r][sub*8];
        float4 xb = *(const float4*)&hs[r][sub*8 + 4];
        float s = xa.x+xa.y+xa.z+xa.w + xb.x+xb.y+xb.z+xb.w;
        s += __shfl_xor(s,1); s += __shfl_xor(s,2);
        s += __shfl_xor(s,4); s += __shfl_xor(s,8);
        float m = s * (1.0f/128.0f);
        float d0=xa.x-m, d1=xa.y-m, d2=xa.z-m, d3=xa.w-m;
        float d4=xb.x-m, d5=xb.y-m, d6=xb.z-m, d7=xb.w-m;
        float vs = d0*d0+d1*d1+d2*d2+d3*d3+d4*d4+d5*d5+d6*d6+d7*d7;
        vs += __shfl_xor(vs,1); vs += __shfl_xor(vs,2);
        vs += __shfl_xor(vs,4); vs += __shfl_xor(vs,8);
        float inv = 1.0f / sqrtf(vs * (1.0f/128.0f) + 1e-5f);
        float4 ga = *(const float4*)&lng[sub*8], gb = *(const float4*)&lng[sub*8+4];
        float4 ba = *(const float4*)&lnb[sub*8], bb = *(const float4*)&lnb[sub*8+4];
        bf16x8 vv;
        vv[0] = (short)f2bf(d0*inv*ga.x + ba.x);
        vv[1] = (short)f2bf(d1*inv*ga.y + ba.y);
        vv[2] = (short)f2bf(d2*inv*ga.z + ba.z);
        vv[3] = (short)f2bf(d3*inv*ga.w + ba.w);
        vv[4] = (short)f2bf(d4*inv*gb.x + bb.x);
        vv[5] = (short)f2bf(d5*inv*gb.y + bb.y);
        vv[6] = (short)f2bf(d6*inv*gb.z + bb.z);
        vv[7] = (short)f2bf(d7*inv*gb.w + bb.w);
        *(bf16x8*)&Albf[r][sub*8] = vv;
    }
    __syncthreads();

    // FF1: each wave computes C1[16 x 128] at cols w*128
    f32x4 acc1[8];
    #pragma unroll
    for (int i = 0; i < 8; i++) acc1[i] = (f32x4){0.f, 0.f, 0.f, 0.f};
    {
        const unsigned short* w1p = W1T + (size_t)(w*128 + fr)*128 + kg*8;
        #pragma unroll
        for (int ks = 0; ks < 4; ks++) {
            bf16x8 af = *(const bf16x8*)&Albf[fr][ks*32 + kg*8];
            #pragma unroll
            for (int nt = 0; nt < 8; nt++) {
                bf16x8 bf = *(const bf16x8*)(w1p + nt*16*128 + ks*32);
                acc1[nt] = __builtin_amdgcn_mfma_f32_16x16x32_bf16(af, bf, acc1[nt], 0, 0, 0);
            }
        }
    }
    // bias + GELU -> bf16 activations
    #pragma unroll
    for (int nt = 0; nt < 8; nt++) {
        int col = w*128 + nt*16 + fr;
        float bias = b1[col];
        #pragma unroll
        for (int i = 0; i < 4; i++) {
            int row = kg*4 + i;
            float x = acc1[nt][i] + bias;
            float t0 = tanhf(0.7978845608028654f * (x + 0.044715f*x*x*x));
            albf[row][col] = f2bf(0.5f*x*(1.0f + t0));
        }
    }
    __syncthreads();

    // FF2: each wave computes D2[16 x 32] at cols w*32; write h = hs + D2 + b2
    f32x4 acc2[2];
    acc2[0] = (f32x4){0.f,0.f,0.f,0.f};
    acc2[1] = (f32x4){0.f,0.f,0.f,0.f};
    {
        const unsigned short* w2p = W2T + (size_t)(w*32 + fr)*512 + kg*8;
        #pragma unroll
        for (int ks = 0; ks < 16; ks++) {
            bf16x8 af = *(const bf16x8*)&albf[fr][ks*32 + kg*8];
            bf16x8 b0 = *(const bf16x8*)(w2p + ks*32);
            bf16x8 b1f = *(const bf16x8*)(w2p + 16*512 + ks*32);
            acc2[0] = __builtin_amdgcn_mfma_f32_16x16x32_bf16(af, b0, acc2[0], 0, 0, 0);
            acc2[1] = __builtin_amdgcn_mfma_f32_16x16x32_bf16(af, b1f, acc2[1], 0, 0, 0);
        }
    }
    #pragma unroll
    for (int nt = 0; nt < 2; nt++) {
        int col = w*32 + nt*16 + fr;
        float bias = b2[col];
        #pragma unroll
        for (int i = 0; i < 4; i++) {
            int row = kg*4 + i;
            h[(size_t)(row0 + row)*DD + col] = hs[row][col] + acc2[nt][i] + bias;
        }
    }
}

// ---------------- two-stage pool ----------------
__global__ void k_pool(const float* __restrict__ h, float* __restrict__ partial) {
    int blk = blockIdx.x;              // b*64 + c
    int t = threadIdx.x;               // 128
    int b = blk >> 6, c = blk & 63;
    const float* hp = h + ((size_t)b*SS + c*32)*DD + t;
    float acc = 0.f;
    #pragma unroll
    for (int i = 0; i < 32; i++) acc += hp[i*DD];
    partial[blk*DD + t] = acc;
}

__global__ void k_final(const float* __restrict__ partial, const float* __restrict__ fcW,
                        const float* __restrict__ fcb, float* __restrict__ out) {
    __shared__ float red[4];
    int b = blockIdx.x, t = threadIdx.x;   // 128 threads
    const float* pp = partial + (size_t)b*64*DD + t;
    float acc = 0.f;
    #pragma unroll
    for (int c = 0; c < 64; c++) acc += pp[c*DD];
    float pooled = acc * (1.0f/(float)SS);
    float p0 = pooled * fcW[t*2+0];
    float p1 = pooled * fcW[t*2+1];
    #pragma unroll
    for (int o = 32; o >= 1; o >>= 1) { p0 += __shfl_xor(p0,o); p1 += __shfl_xor(p1,o); }
    int w = t >> 6;
    if ((t & 63) == 0) { red[w*2] = p0; red[w*2+1] = p1; }
    __syncthreads();
    if (t == 0) {
        out[b*2 + 0] = red[0] + red[2] + fcb[0];
        out[b*2 + 1] = red[1] + red[3] + fcb[1];
    }
}

extern "C" void kernel_launch(void* const* d_in, const int* in_sizes, int n_in,
                              void* d_out, int out_size, void* d_ws, size_t ws_size,
                              hipStream_t stream) {
    const float* x    = (const float*)d_in[0];
    const float* embW = (const float*)d_in[1];
    const float* embB = (const float*)d_in[2];
    const float* Wqk  = (const float*)d_in[3];
    const float* Wv   = (const float*)d_in[4];
    const float* Wo   = (const float*)d_in[5];
    const float* R    = (const float*)d_in[6];
    const float* ln1g = (const float*)d_in[7];
    const float* ln1b = (const float*)d_in[8];
    const float* ln2g = (const float*)d_in[9];
    const float* ln2b = (const float*)d_in[10];
    const float* W1   = (const float*)d_in[11];
    const float* b1   = (const float*)d_in[12];
    const float* W2   = (const float*)d_in[13];
    const float* b2   = (const float*)d_in[14];
    const float* fcW  = (const float*)d_in[15];
    const float* fcb  = (const float*)d_in[16];
    float* out = (float*)d_out;

    char* w = (char*)d_ws;
    auto carve = [&](size_t bytes) -> char* {
        char* p = w;
        w += (bytes + 255) & ~(size_t)255;
        return p;
    };
    float* h       = (float*)carve((size_t)BB*SS*DD*4);
    float* qk      = (float*)carve((size_t)NBH*SS*DH*4);
    _Float16* kn16 = (_Float16*)carve((size_t)NBH*SS*DH*2);
    _Float16* v16  = (_Float16*)carve((size_t)NBH*SS*DH*2);
    float* nrmg    = (float*)carve((size_t)NBH*SS*4);
    int*   bkt     = (int*)  carve((size_t)NBH*LL*4);
    int*   sticker = (int*)  carve((size_t)NBH*LL*4);
    _Float16* so   = (_Float16*)carve((size_t)NBH*LL*DH*2);
    float* slog    = (float*)carve((size_t)NBH*LL*4);
    float* partial = (float*)carve((size_t)BB*64*DD*4);
    unsigned short* w1t = (unsigned short*)carve((size_t)DEPTH*DD*DFF*2);
    unsigned short* w2t = (unsigned short*)carve((size_t)DEPTH*DFF*DD*2);
    _Float16* wqk16 = (_Float16*)carve((size_t)DEPTH*DD*DD*2);
    _Float16* wv16  = (_Float16*)carve((size_t)DEPTH*DD*DD*2);
    _Float16* wo16  = (_Float16*)carve((size_t)DEPTH*DD*DD*2);

    // one-time per call: transpose + cast weights (all layers)
    k_wcast<<<dim3(DFF/32, DD/32, DEPTH), dim3(32, 8), 0, stream>>>(W1, w1t, DD, DFF);
    k_wcast<<<dim3(DD/32, DFF/32, DEPTH), dim3(32, 8), 0, stream>>>(W2, w2t, DFF, DD);
    k_wcast16<<<dim3(DD/32, DD/32, DEPTH), dim3(32, 8), 0, stream>>>(Wqk, wqk16, DD, DD);
    k_wcast16<<<dim3(DD/32, DD/32, DEPTH), dim3(32, 8), 0, stream>>>(Wv, wv16, DD, DD);
    k_wcast16<<<dim3(DD/32, DD/32, DEPTH), dim3(32, 8), 0, stream>>>(Wo, wo16, DD, DD);

    k_embed<<<(BB*SS*DD)/256, 256, 0, stream>>>(x, embW, embB, h);

    for (int l = 0; l < DEPTH; l++) {
        const _Float16* wqkl = wqk16 + (size_t)l*DD*DD;
        const _Float16* wvl  = wv16  + (size_t)l*DD*DD;
        const _Float16* wol  = wo16  + (size_t)l*DD*DD;
        const float* rl  = R   + (size_t)l*HH*DH*NHASH*16;
        const float* g1  = ln1g + l*DD; const float* bg1 = ln1b + l*DD;
        const float* g2  = ln2g + l*DD; const float* bg2 = ln2b + l*DD;
        const unsigned short* w1l = w1t + (size_t)l*DD*DFF;
        const unsigned short* w2l = w2t + (size_t)l*DFF*DD;
        const float* bb1 = b1 + l*DFF;
        const float* bb2 = b2 + l*DD;

        k_proj_qkv<<<(BB*SS)/16, 256, 0, stream>>>(h, g1, bg1, wqkl, wvl,
                                                   qk, kn16, v16, nrmg);
        k_hash<<<(NBH*NHASH*SS)/256, 256, 0, stream>>>(qk, rl, bkt);
        k_scatter<<<NBH*NHASH, 256, 0, stream>>>(bkt, sticker);
        k_attn<<<NBH*NCHUNK, 256, 0, stream>>>(kn16, v16, nrmg, sticker, so, slog);
        k_out_ffn<<<(BB*SS)/16, 256, 0, stream>>>(so, slog, wol, g2, bg2,
                                                  w1l, bb1, w2l, bb2, h);
    }

    k_pool<<<BB*64, 128, 0, stream>>>(h, partial);
    k_final<<<BB, 128, 0, stream>>>(partial, fcW, fcb, out);
}